// Round 6
// baseline (2937.798 us; speedup 1.0000x reference)
//
#include <hip/hip_runtime.h>
#include <hip/hip_bf16.h>

// Problem constants (GraphGRUCell_62019327754706)
// DTYPES (settled r4/r5): all float tensors FP32 in and out. int32 edges.
#define BB 4
#define NN 20000
#define UU 64
#define EE 640000
#define FF 65              // U + D
#define SCALE_F 0.125f     // 1/sqrt(64)
#define NEG_F  -1e30f

static inline size_t align_up(size_t x) { return (x + 255) & ~(size_t)255; }

// ---------------------------------------------------------------- CSR build
__global__ __launch_bounds__(256) void hist_kernel(const int* __restrict__ edst,
                                                   int* __restrict__ counts) {
    int e = blockIdx.x * 256 + threadIdx.x;
    if (e < EE) {
        int d = edst[e];
        if ((unsigned)d < (unsigned)NN) atomicAdd(&counts[d], 1);
    }
}

__global__ __launch_bounds__(1024) void scan_kernel(const int* __restrict__ counts,
                                                    int* __restrict__ off,
                                                    int* __restrict__ cursor) {
    __shared__ int sd[1024];
    __shared__ int carry_s;
    int tid = threadIdx.x;
    if (tid == 0) carry_s = 0;
    __syncthreads();
    for (int base = 0; base < NN; base += 1024) {
        int i = base + tid;
        int val = (i < NN) ? counts[i] : 0;
        sd[tid] = val;
        __syncthreads();
        for (int d = 1; d < 1024; d <<= 1) {   // Hillis-Steele inclusive scan
            int t = (tid >= d) ? sd[tid - d] : 0;
            __syncthreads();
            sd[tid] += t;
            __syncthreads();
        }
        int incl = sd[tid];
        int excl = carry_s + incl - val;
        if (i < NN) { off[i] = excl; cursor[i] = excl; }
        __syncthreads();
        if (tid == 1023) carry_s += sd[1023];
        __syncthreads();
    }
    if (tid == 0) off[NN] = carry_s;           // == EE
}

__global__ __launch_bounds__(256) void scatter_kernel(const int* __restrict__ edst,
                                                      const int* __restrict__ esrc,
                                                      int* __restrict__ cursor,
                                                      int* __restrict__ psrc) {
    int e = blockIdx.x * 256 + threadIdx.x;
    if (e < EE) {
        int d = edst[e];
        if ((unsigned)d < (unsigned)NN) {
            int p = atomicAdd(&cursor[d], 1);
            if ((unsigned)p < (unsigned)EE) psrc[p] = esrc[e];
        }
    }
}

// WkT[u*64 + f] = Wk[f*64 + u]  (u,f in [0,64)) — coalesced qk GEMV reads
__global__ __launch_bounds__(256) void wkt_kernel(const float* __restrict__ Wk,
                                                  float* __restrict__ WkT) {
    int idx = blockIdx.x * 256 + threadIdx.x;
    if (idx < UU * UU) {
        int u = idx >> 6, f = idx & 63;
        WkT[idx] = Wk[f * UU + u];
    }
}

// ------------------------- fully fused: proj + softmax-agg (kv-free) + GRU
// One wave per (b,n). Edge loop: 64-edge tiles, lane = edge in phase A
// (per-lane dot of qk with gathered row), lane = channel in phase B.
__global__ __launch_bounds__(256, 4) void fused_kernel(
    const float* __restrict__ state, const float* __restrict__ inputs,
    const float* __restrict__ Wq, const float* __restrict__ bq,
    const float* __restrict__ Wk, const float* __restrict__ WkT,
    const float* __restrict__ bk,
    const float* __restrict__ Wv, const float* __restrict__ bv,
    const float* __restrict__ Ws, const float* __restrict__ bs,
    const float* __restrict__ W1, const float* __restrict__ b1,
    const float* __restrict__ W2, const float* __restrict__ b2,
    const int* __restrict__ off, const int* __restrict__ psrc,
    float* __restrict__ out) {
    int w = threadIdx.x >> 6, lane = threadIdx.x & 63;
    int g = blockIdx.x * 4 + w;               // g = b*NN + n
    int b = g / NN, n = g - b * NN;
    size_t o = (size_t)g * UU + lane;
    __shared__ float xsL[4][68];              // x row (65), reused as qk (65)
    __shared__ float qsL[4][64];              // q vector, reused for xacc
    __shared__ float h2L[4][64];

    float hval = state[o];
    float xinv = inputs[g];
    xsL[w][lane] = hval;
    if (lane == 0) xsL[w][64] = xinv;
    __syncthreads();                          // A

    // q (pre-scaled 1/8) and x@Ws + bs   (coalesced weight reads)
    float aq = 0.f, as_ = 0.f;
    for (int f = 0; f < FF; ++f) {
        float xv = xsL[w][f];
        aq  += xv * Wq[f * UU + lane];
        as_ += xv * Ws[f * UU + lane];
    }
    aq = (aq + bq[lane]) * SCALE_F;
    as_ += bs[lane];
    qsL[w][lane] = aq;
    __syncthreads();                          // B

    // qk[f=lane] = sum_u WkT[u*64+lane] * q[u]   (coalesced)
    float qk = 0.f;
    for (int u = 0; u < UU; ++u)
        qk += WkT[u * UU + lane] * qsL[w][u];
    // uniform terms via one butterfly (two independent chains)
    float t64 = Wk[UU * UU + lane] * aq;      // Wk row 64 (xin row)
    float tbk = bk[lane] * aq;
#pragma unroll
    for (int d = 1; d < 64; d <<= 1) {
        t64 += __shfl_xor(t64, d, 64);
        tbk += __shfl_xor(tbk, d, 64);
    }
    float qbk = tbk;                          // uniform
    __syncthreads();                          // C (xs reads all done)
    xsL[w][lane] = qk;                        // reuse xs as qk[0..63]
    if (lane == 0) xsL[w][64] = t64;          // qk64
    __syncthreads();                          // D

    bool mg = (__shfl(hval, 58, 64) != 0.0f); // dst node mask, wave-uniform

    float m = NEG_F, l = 0.f, xax = 0.f;
    float acc0 = 0.f, acc1 = 0.f, acc2 = 0.f, acc3 = 0.f;
    if (mg) {
        int i0 = off[n], i1 = off[n + 1];
        i0 = max(0, min(i0, EE));
        i1 = max(i0, min(i1, EE));
        const float* stb = state  + (size_t)b * NN * UU;
        const float* inb = inputs + (size_t)b * NN;
        float qk64 = xsL[w][64];
        for (int i = i0; i < i1; i += 64) {
            int tlen = min(64, i1 - i);
            // ---- phase A: lane = edge ----
            int  s_e  = (lane < tlen) ? psrc[i + lane] : -1;
            bool valid = ((unsigned)s_e < (unsigned)NN);
            int  srow = valid ? s_e : 0;
            float sc = NEG_F;
            float xins = 0.f;
            bool act = false;
            if (valid) {
                const float* rp = stb + (size_t)s_e * UU;
                float d0 = 0.f, d1 = 0.f, d2 = 0.f, d3 = 0.f, m58 = 0.f;
#pragma unroll
                for (int u4 = 0; u4 < 16; ++u4) {
                    float4 r  = *(const float4*)(rp + u4 * 4);
                    float4 qv = *(const float4*)&xsL[w][u4 * 4];
                    if (u4 == 14) m58 = r.z;          // element 58 = src mask
                    d0 += r.x * qv.x; d1 += r.y * qv.y;
                    d2 += r.z * qv.z; d3 += r.w * qv.w;
                }
                if (m58 != 0.f) {
                    act = true;
                    xins = inb[s_e];
                    sc = (d0 + d1) + (d2 + d3) + qk64 * xins + qbk;
                }
            }
            // ---- tile softmax merge (once per tile, not per edge) ----
            float mt = sc;
#pragma unroll
            for (int d = 1; d < 64; d <<= 1) mt = fmaxf(mt, __shfl_xor(mt, d, 64));
            float mnew = fmaxf(m, mt);
            float scale = __expf(m - mnew);   // both NEG -> 1, but l=acc=0
            float p = act ? __expf(sc - mnew) : 0.f;
            float ps = p, pxs = p * xins;
#pragma unroll
            for (int d = 1; d < 64; d <<= 1) {
                ps  += __shfl_xor(ps, d, 64);
                pxs += __shfl_xor(pxs, d, 64);
            }
            l   = l   * scale + ps;
            xax = xax * scale + pxs;
            m = mnew;
            // ---- phase B: lane = channel ----
            acc0 *= scale; acc1 *= scale; acc2 *= scale; acc3 *= scale;
            for (int j0 = 0; j0 < 64; j0 += 8) {
                if (j0 >= tlen) break;        // uniform exit
#pragma unroll
                for (int jj = 0; jj < 8; ++jj) {
                    int j = j0 + jj;
                    float pj = __shfl(p, j, 64);     // uniform j -> readlane
                    int   sj = __shfl(srow, j, 64);
                    float hv = stb[(size_t)sj * UU + lane];  // coalesced, L1-hot
                    if ((jj & 3) == 0) acc0 += pj * hv;
                    else if ((jj & 3) == 1) acc1 += pj * hv;
                    else if ((jj & 3) == 2) acc2 += pj * hv;
                    else acc3 += pj * hv;
                }
            }
        }
    }
    qsL[w][lane] = (acc0 + acc1) + (acc2 + acc3);   // xacc broadcast
    __syncthreads();                          // E

    float h2;
    if (mg) {
        float agg = 0.f;
        if (l > 0.f) {
            float num = 0.f;
            for (int f = 0; f < UU; ++f)
                num += Wv[f * UU + lane] * qsL[w][f];
            num += Wv[UU * UU + lane] * xax;
            agg = num / fmaxf(l, 1e-16f) + bv[lane];
        }
        h2 = agg + as_;
    } else {
        h2 = hval;                            // masked node: pass-through h
    }

    h2L[w][lane] = h2;
    __syncthreads();                          // F

    // value = sigmoid([xin, h2] @ W1 + b1); lane computes cols lane, 64+lane
    float a1 = xinv * W1[lane];
    float a2 = xinv * W1[UU + lane];
    for (int f = 0; f < UU; ++f) {
        float hv = h2L[w][f];
        a1 += hv * W1[(f + 1) * 128 + lane];
        a2 += hv * W1[(f + 1) * 128 + UU + lane];
    }
    a1 += b1[lane];
    a2 += b1[UU + lane];
    float reset = 1.f / (1.f + __expf(-a1));
    float z     = 1.f / (1.f + __expf(-a2));

    __syncthreads();                          // G (before overwrite)
    h2L[w][lane] = reset * h2;
    __syncthreads();                          // H

    // c = tanh([xin, reset*h2] @ W2 + b2)
    float a3 = xinv * W2[lane];
    for (int f = 0; f < UU; ++f)
        a3 += h2L[w][f] * W2[(f + 1) * UU + lane];
    a3 += b2[lane];
    float aa = fabsf(a3);
    float tt = __expf(-2.f * aa);
    float c  = copysignf((1.f - tt) / (1.f + tt), a3);  // overflow-safe tanh

    out[o] = (1.f - z) * h2 + z * c;          // FP32 store
}

// ------------------------------------------------------------------- launch
extern "C" void kernel_launch(void* const* d_in, const int* in_sizes, int n_in,
                              void* d_out, int out_size, void* d_ws, size_t ws_size,
                              hipStream_t stream) {
    const float* inputs = (const float*)d_in[0];
    const float* state  = (const float*)d_in[1];
    if (in_sizes[0] != BB * NN) { inputs = (const float*)d_in[1]; state = (const float*)d_in[0]; }
    const int*   esrc   = (const int*)d_in[2];
    const int*   edst   = (const int*)d_in[3];
    const float* Wq = (const float*)d_in[4];
    const float* bq = (const float*)d_in[5];
    const float* Wk = (const float*)d_in[6];
    const float* bk = (const float*)d_in[7];
    const float* Wv = (const float*)d_in[8];
    const float* bv = (const float*)d_in[9];
    const float* Ws = (const float*)d_in[10];
    const float* bs = (const float*)d_in[11];
    const float* W1 = (const float*)d_in[12];
    const float* b1 = (const float*)d_in[13];
    const float* W2 = (const float*)d_in[14];
    const float* b2 = (const float*)d_in[15];
    float* out = (float*)d_out;

    // workspace carve — CSR + WkT, ~2.85 MB total (round-5 proven safe)
    char* base = (char*)d_ws;
    size_t ofs = 0;
    int* counts = (int*)(base + ofs); ofs = align_up(ofs + (size_t)NN * 4);
    int* offp   = (int*)(base + ofs); ofs = align_up(ofs + (size_t)(NN + 1) * 4);
    int* cursor = (int*)(base + ofs); ofs = align_up(ofs + (size_t)NN * 4);
    int* psrc   = (int*)(base + ofs); ofs = align_up(ofs + (size_t)EE * 4);
    float* WkT  = (float*)(base + ofs); ofs = align_up(ofs + (size_t)UU * UU * 4);
    (void)ws_size; (void)n_in; (void)out_size;

    hipMemsetAsync(counts, 0, (size_t)NN * 4, stream);
    hist_kernel<<<(EE + 255) / 256, 256, 0, stream>>>(edst, counts);
    scan_kernel<<<1, 1024, 0, stream>>>(counts, offp, cursor);
    scatter_kernel<<<(EE + 255) / 256, 256, 0, stream>>>(edst, esrc, cursor, psrc);
    wkt_kernel<<<(UU * UU + 255) / 256, 256, 0, stream>>>(Wk, WkT);

    int nodeBlocks = (BB * NN) / 4;   // 20000 blocks, 4 waves each
    fused_kernel<<<nodeBlocks, 256, 0, stream>>>(state, inputs, Wq, bq, Wk, WkT,
                                                 bk, Wv, bv, Ws, bs, W1, b1,
                                                 W2, b2, offp, psrc, out);
}

// Round 7
// 1346.693 us; speedup vs baseline: 2.1815x; 2.1815x over previous
//
#include <hip/hip_runtime.h>
#include <hip/hip_bf16.h>

// Problem constants (GraphGRUCell_62019327754706)
// DTYPES (settled r4/r5): all float tensors FP32 in and out. int32 edges.
// r6 lesson: __launch_bounds__(256,4) -> VGPR capped at 64 -> massive scratch
// spills (4.48 GB WRITE_SIZE). Keep launch_bounds un-clamped.
#define BB 4
#define NN 20000
#define UU 64
#define EE 640000
#define FF 65              // U + D
#define SCALE_F 0.125f     // 1/sqrt(64)
#define NEG_F  -1e30f

static inline size_t align_up(size_t x) { return (x + 255) & ~(size_t)255; }

// ---------------------------------------------------------------- CSR build
__global__ __launch_bounds__(256) void hist_kernel(const int* __restrict__ edst,
                                                   int* __restrict__ counts) {
    int e = blockIdx.x * 256 + threadIdx.x;
    if (e < EE) {
        int d = edst[e];
        if ((unsigned)d < (unsigned)NN) atomicAdd(&counts[d], 1);
    }
}

__global__ __launch_bounds__(1024) void scan_kernel(const int* __restrict__ counts,
                                                    int* __restrict__ off,
                                                    int* __restrict__ cursor) {
    __shared__ int sd[1024];
    __shared__ int carry_s;
    int tid = threadIdx.x;
    if (tid == 0) carry_s = 0;
    __syncthreads();
    for (int base = 0; base < NN; base += 1024) {
        int i = base + tid;
        int val = (i < NN) ? counts[i] : 0;
        sd[tid] = val;
        __syncthreads();
        for (int d = 1; d < 1024; d <<= 1) {   // Hillis-Steele inclusive scan
            int t = (tid >= d) ? sd[tid - d] : 0;
            __syncthreads();
            sd[tid] += t;
            __syncthreads();
        }
        int incl = sd[tid];
        int excl = carry_s + incl - val;
        if (i < NN) { off[i] = excl; cursor[i] = excl; }
        __syncthreads();
        if (tid == 1023) carry_s += sd[1023];
        __syncthreads();
    }
    if (tid == 0) off[NN] = carry_s;           // == EE
}

__global__ __launch_bounds__(256) void scatter_kernel(const int* __restrict__ edst,
                                                      const int* __restrict__ esrc,
                                                      int* __restrict__ cursor,
                                                      int* __restrict__ psrc) {
    int e = blockIdx.x * 256 + threadIdx.x;
    if (e < EE) {
        int d = edst[e];
        if ((unsigned)d < (unsigned)NN) {
            int p = atomicAdd(&cursor[d], 1);
            if ((unsigned)p < (unsigned)EE) psrc[p] = esrc[e];
        }
    }
}

// WkT[u*64 + f] = Wk[f*64 + u]  (u,f in [0,64)) — coalesced qk GEMV reads
__global__ __launch_bounds__(256) void wkt_kernel(const float* __restrict__ Wk,
                                                  float* __restrict__ WkT) {
    int idx = blockIdx.x * 256 + threadIdx.x;
    if (idx < UU * UU) {
        int u = idx >> 6, f = idx & 63;
        WkT[idx] = Wk[f * UU + u];
    }
}

// ------------------------- fully fused: proj + softmax-agg (kv-free) + GRU
// One wave per (b,n). Edge loop: 64-edge tiles, lane = edge in phase A
// (per-lane dot of qk with gathered row), lane = channel in phase B.
__global__ __launch_bounds__(256) void fused_kernel(
    const float* __restrict__ state, const float* __restrict__ inputs,
    const float* __restrict__ Wq, const float* __restrict__ bq,
    const float* __restrict__ Wk, const float* __restrict__ WkT,
    const float* __restrict__ bk,
    const float* __restrict__ Wv, const float* __restrict__ bv,
    const float* __restrict__ Ws, const float* __restrict__ bs,
    const float* __restrict__ W1, const float* __restrict__ b1,
    const float* __restrict__ W2, const float* __restrict__ b2,
    const int* __restrict__ off, const int* __restrict__ psrc,
    float* __restrict__ out) {
    int w = threadIdx.x >> 6, lane = threadIdx.x & 63;
    int g = blockIdx.x * 4 + w;               // g = b*NN + n
    int b = g / NN, n = g - b * NN;
    size_t o = (size_t)g * UU + lane;
    __shared__ float xsL[4][68];              // x row (65), reused as qk (65)
    __shared__ float qsL[4][64];              // q vector, reused for xacc
    __shared__ float h2L[4][64];

    float hval = state[o];
    float xinv = inputs[g];
    xsL[w][lane] = hval;
    if (lane == 0) xsL[w][64] = xinv;
    __syncthreads();                          // A

    // q (pre-scaled 1/8) and x@Ws + bs   (coalesced weight reads)
    float aq = 0.f, as_ = 0.f;
    for (int f = 0; f < FF; ++f) {
        float xv = xsL[w][f];
        aq  += xv * Wq[f * UU + lane];
        as_ += xv * Ws[f * UU + lane];
    }
    aq = (aq + bq[lane]) * SCALE_F;
    as_ += bs[lane];
    qsL[w][lane] = aq;
    __syncthreads();                          // B

    // qk[f=lane] = sum_u WkT[u*64+lane] * q[u]   (coalesced)
    float qk = 0.f;
    for (int u = 0; u < UU; ++u)
        qk += WkT[u * UU + lane] * qsL[w][u];
    // uniform terms via one butterfly (two independent chains)
    float t64 = Wk[UU * UU + lane] * aq;      // Wk row 64 (xin row)
    float tbk = bk[lane] * aq;
#pragma unroll
    for (int d = 1; d < 64; d <<= 1) {
        t64 += __shfl_xor(t64, d, 64);
        tbk += __shfl_xor(tbk, d, 64);
    }
    float qbk = tbk;                          // uniform
    __syncthreads();                          // C (xs reads all done)
    xsL[w][lane] = qk;                        // reuse xs as qk[0..63]
    if (lane == 0) xsL[w][64] = t64;          // qk64
    __syncthreads();                          // D

    bool mg = (__shfl(hval, 58, 64) != 0.0f); // dst node mask, wave-uniform

    float m = NEG_F, l = 0.f, xax = 0.f;
    float acc0 = 0.f, acc1 = 0.f, acc2 = 0.f, acc3 = 0.f;
    if (mg) {
        int i0 = off[n], i1 = off[n + 1];
        i0 = max(0, min(i0, EE));
        i1 = max(i0, min(i1, EE));
        const float* stb = state  + (size_t)b * NN * UU;
        const float* inb = inputs + (size_t)b * NN;
        float qk64 = xsL[w][64];
        for (int i = i0; i < i1; i += 64) {
            int tlen = min(64, i1 - i);
            // ---- phase A: lane = edge ----
            int  s_e  = (lane < tlen) ? psrc[i + lane] : -1;
            bool valid = ((unsigned)s_e < (unsigned)NN);
            int  srow = valid ? s_e : 0;
            float sc = NEG_F;
            float xins = 0.f;
            bool act = false;
            if (valid) {
                const float* rp = stb + (size_t)s_e * UU;
                float d0 = 0.f, d1 = 0.f, d2 = 0.f, d3 = 0.f, m58 = 0.f;
#pragma unroll
                for (int u4 = 0; u4 < 16; ++u4) {
                    float4 r  = *(const float4*)(rp + u4 * 4);
                    float4 qv = *(const float4*)&xsL[w][u4 * 4];
                    if (u4 == 14) m58 = r.z;          // element 58 = src mask
                    d0 += r.x * qv.x; d1 += r.y * qv.y;
                    d2 += r.z * qv.z; d3 += r.w * qv.w;
                }
                if (m58 != 0.f) {
                    act = true;
                    xins = inb[s_e];
                    sc = (d0 + d1) + (d2 + d3) + qk64 * xins + qbk;
                }
            }
            // ---- tile softmax merge (once per tile, not per edge) ----
            float mt = sc;
#pragma unroll
            for (int d = 1; d < 64; d <<= 1) mt = fmaxf(mt, __shfl_xor(mt, d, 64));
            float mnew = fmaxf(m, mt);
            float scale = __expf(m - mnew);   // both NEG -> 1, but l=acc=0
            float p = act ? __expf(sc - mnew) : 0.f;
            float ps = p, pxs = p * xins;
#pragma unroll
            for (int d = 1; d < 64; d <<= 1) {
                ps  += __shfl_xor(ps, d, 64);
                pxs += __shfl_xor(pxs, d, 64);
            }
            l   = l   * scale + ps;
            xax = xax * scale + pxs;
            m = mnew;
            // ---- phase B: lane = channel ----
            acc0 *= scale; acc1 *= scale; acc2 *= scale; acc3 *= scale;
            for (int j0 = 0; j0 < 64; j0 += 8) {
                if (j0 >= tlen) break;        // uniform exit
#pragma unroll
                for (int jj = 0; jj < 8; ++jj) {
                    int j = j0 + jj;
                    float pj = __shfl(p, j, 64);     // uniform j -> readlane
                    int   sj = __shfl(srow, j, 64);
                    float hv = stb[(size_t)sj * UU + lane];  // coalesced, L1-hot
                    if ((jj & 3) == 0) acc0 += pj * hv;
                    else if ((jj & 3) == 1) acc1 += pj * hv;
                    else if ((jj & 3) == 2) acc2 += pj * hv;
                    else acc3 += pj * hv;
                }
            }
        }
    }
    qsL[w][lane] = (acc0 + acc1) + (acc2 + acc3);   // xacc broadcast
    __syncthreads();                          // E

    float h2;
    if (mg) {
        float agg = 0.f;
        if (l > 0.f) {
            float num = 0.f;
            for (int f = 0; f < UU; ++f)
                num += Wv[f * UU + lane] * qsL[w][f];
            num += Wv[UU * UU + lane] * xax;
            agg = num / fmaxf(l, 1e-16f) + bv[lane];
        }
        h2 = agg + as_;
    } else {
        h2 = hval;                            // masked node: pass-through h
    }

    h2L[w][lane] = h2;
    __syncthreads();                          // F

    // value = sigmoid([xin, h2] @ W1 + b1); lane computes cols lane, 64+lane
    float a1 = xinv * W1[lane];
    float a2 = xinv * W1[UU + lane];
    for (int f = 0; f < UU; ++f) {
        float hv = h2L[w][f];
        a1 += hv * W1[(f + 1) * 128 + lane];
        a2 += hv * W1[(f + 1) * 128 + UU + lane];
    }
    a1 += b1[lane];
    a2 += b1[UU + lane];
    float reset = 1.f / (1.f + __expf(-a1));
    float z     = 1.f / (1.f + __expf(-a2));

    __syncthreads();                          // G (before overwrite)
    h2L[w][lane] = reset * h2;
    __syncthreads();                          // H

    // c = tanh([xin, reset*h2] @ W2 + b2)
    float a3 = xinv * W2[lane];
    for (int f = 0; f < UU; ++f)
        a3 += h2L[w][f] * W2[(f + 1) * UU + lane];
    a3 += b2[lane];
    float aa = fabsf(a3);
    float tt = __expf(-2.f * aa);
    float c  = copysignf((1.f - tt) / (1.f + tt), a3);  // overflow-safe tanh

    out[o] = (1.f - z) * h2 + z * c;          // FP32 store
}

// ------------------------------------------------------------------- launch
extern "C" void kernel_launch(void* const* d_in, const int* in_sizes, int n_in,
                              void* d_out, int out_size, void* d_ws, size_t ws_size,
                              hipStream_t stream) {
    const float* inputs = (const float*)d_in[0];
    const float* state  = (const float*)d_in[1];
    if (in_sizes[0] != BB * NN) { inputs = (const float*)d_in[1]; state = (const float*)d_in[0]; }
    const int*   esrc   = (const int*)d_in[2];
    const int*   edst   = (const int*)d_in[3];
    const float* Wq = (const float*)d_in[4];
    const float* bq = (const float*)d_in[5];
    const float* Wk = (const float*)d_in[6];
    const float* bk = (const float*)d_in[7];
    const float* Wv = (const float*)d_in[8];
    const float* bv = (const float*)d_in[9];
    const float* Ws = (const float*)d_in[10];
    const float* bs = (const float*)d_in[11];
    const float* W1 = (const float*)d_in[12];
    const float* b1 = (const float*)d_in[13];
    const float* W2 = (const float*)d_in[14];
    const float* b2 = (const float*)d_in[15];
    float* out = (float*)d_out;

    // workspace carve — CSR + WkT, ~2.85 MB total (round-5 proven safe)
    char* base = (char*)d_ws;
    size_t ofs = 0;
    int* counts = (int*)(base + ofs); ofs = align_up(ofs + (size_t)NN * 4);
    int* offp   = (int*)(base + ofs); ofs = align_up(ofs + (size_t)(NN + 1) * 4);
    int* cursor = (int*)(base + ofs); ofs = align_up(ofs + (size_t)NN * 4);
    int* psrc   = (int*)(base + ofs); ofs = align_up(ofs + (size_t)EE * 4);
    float* WkT  = (float*)(base + ofs); ofs = align_up(ofs + (size_t)UU * UU * 4);
    (void)ws_size; (void)n_in; (void)out_size;

    hipMemsetAsync(counts, 0, (size_t)NN * 4, stream);
    hist_kernel<<<(EE + 255) / 256, 256, 0, stream>>>(edst, counts);
    scan_kernel<<<1, 1024, 0, stream>>>(counts, offp, cursor);
    scatter_kernel<<<(EE + 255) / 256, 256, 0, stream>>>(edst, esrc, cursor, psrc);
    wkt_kernel<<<(UU * UU + 255) / 256, 256, 0, stream>>>(Wk, WkT);

    int nodeBlocks = (BB * NN) / 4;   // 20000 blocks, 4 waves each
    fused_kernel<<<nodeBlocks, 256, 0, stream>>>(state, inputs, Wq, bq, Wk, WkT,
                                                 bk, Wv, bv, Ws, bs, W1, b1,
                                                 W2, b2, offp, psrc, out);
}

// Round 8
// 444.171 us; speedup vs baseline: 6.6141x; 3.0319x over previous
//
#include <hip/hip_runtime.h>
#include <hip/hip_bf16.h>

// Problem constants (GraphGRUCell_62019327754706)
// DTYPES (settled r4/r5): all float tensors FP32 in and out. int32 edges.
// r6 lesson: never clamp launch_bounds waves -> spills.
// r7 lesson: VGPR 156 => 2 waves/SIMD; bottleneck = per-wave weight
// re-streaming (~9.2 GB L2) + 4-line/edge fp32 gathers.
#define BB 4
#define NN 20000
#define UU 64
#define EE 640000
#define FF 65              // U + D
#define SCALE_F 0.125f     // 1/sqrt(64)
#define NEG_F  -1e30f

typedef unsigned short u16;

static inline size_t align_up(size_t x) { return (x + 255) & ~(size_t)255; }

__device__ __forceinline__ float u2f(unsigned int u) { return __uint_as_float(u); }
__device__ __forceinline__ u16 f2bf(float f) {
    __hip_bfloat16 h = __float2bfloat16(f);
    return *reinterpret_cast<u16*>(&h);
}

// ---------------------------------------------------------------- CSR build
__global__ __launch_bounds__(256) void hist_kernel(const int* __restrict__ edst,
                                                   int* __restrict__ counts) {
    int e = blockIdx.x * 256 + threadIdx.x;
    if (e < EE) {
        int d = edst[e];
        if ((unsigned)d < (unsigned)NN) atomicAdd(&counts[d], 1);
    }
}

__global__ __launch_bounds__(1024) void scan_kernel(const int* __restrict__ counts,
                                                    int* __restrict__ off,
                                                    int* __restrict__ cursor) {
    __shared__ int sd[1024];
    __shared__ int carry_s;
    int tid = threadIdx.x;
    if (tid == 0) carry_s = 0;
    __syncthreads();
    for (int base = 0; base < NN; base += 1024) {
        int i = base + tid;
        int val = (i < NN) ? counts[i] : 0;
        sd[tid] = val;
        __syncthreads();
        for (int d = 1; d < 1024; d <<= 1) {   // Hillis-Steele inclusive scan
            int t = (tid >= d) ? sd[tid - d] : 0;
            __syncthreads();
            sd[tid] += t;
            __syncthreads();
        }
        int incl = sd[tid];
        int excl = carry_s + incl - val;
        if (i < NN) { off[i] = excl; cursor[i] = excl; }
        __syncthreads();
        if (tid == 1023) carry_s += sd[1023];
        __syncthreads();
    }
    if (tid == 0) off[NN] = carry_s;           // == EE
}

__global__ __launch_bounds__(256) void scatter_kernel(const int* __restrict__ edst,
                                                      const int* __restrict__ esrc,
                                                      int* __restrict__ cursor,
                                                      int* __restrict__ psrc) {
    int e = blockIdx.x * 256 + threadIdx.x;
    if (e < EE) {
        int d = edst[e];
        if ((unsigned)d < (unsigned)NN) {
            int p = atomicAdd(&cursor[d], 1);
            if ((unsigned)p < (unsigned)EE) psrc[p] = esrc[e];
        }
    }
}

// WkT[u*64 + f] = Wk[f*64 + u] — only used by the fallback path
__global__ __launch_bounds__(256) void wkt_kernel(const float* __restrict__ Wk,
                                                  float* __restrict__ WkT) {
    int idx = blockIdx.x * 256 + threadIdx.x;
    if (idx < UU * UU) {
        int u = idx >> 6, f = idx & 63;
        WkT[idx] = Wk[f * UU + u];
    }
}

// ----------------------------- prep: k,v (bf16) + mask, 8 nodes per wave
__global__ __launch_bounds__(256) void prep_kernel(
    const float* __restrict__ state, const float* __restrict__ inputs,
    const float* __restrict__ Wk, const float* __restrict__ bk,
    const float* __restrict__ Wv, const float* __restrict__ bv,
    u16* __restrict__ kbuf, u16* __restrict__ vbuf,
    unsigned char* __restrict__ maskb) {
    int w = threadIdx.x >> 6, lane = threadIdx.x & 63;
    int gb = (blockIdx.x * 4 + w) * 8;        // 8 nodes per wave
    __shared__ float xs[4][8][66];
#pragma unroll
    for (int j = 0; j < 8; ++j) {
        int g = gb + j;
        xs[w][j][lane] = state[(size_t)g * UU + lane];
        if (lane == 0) xs[w][j][64] = inputs[g];
    }
    __syncthreads();                          // uniform

    float ak[8], av[8];
#pragma unroll
    for (int j = 0; j < 8; ++j) { ak[j] = 0.f; av[j] = 0.f; }
    for (int f = 0; f < FF; ++f) {            // weight loaded once, 8 nodes reuse
        float wk = Wk[f * UU + lane], wv = Wv[f * UU + lane];
#pragma unroll
        for (int j = 0; j < 8; ++j) {
            float xv = xs[w][j][f];
            ak[j] += xv * wk; av[j] += xv * wv;
        }
    }
    float bkl = bk[lane], bvl = bv[lane];
#pragma unroll
    for (int j = 0; j < 8; ++j) {
        int g = gb + j;
        kbuf[(size_t)g * UU + lane] = f2bf(ak[j] + bkl);
        vbuf[(size_t)g * UU + lane] = f2bf(av[j] + bvl);
        if (lane == 0) maskb[g] = (xs[w][j][58] != 0.0f) ? 1 : 0;
    }
}

// -------------------- fast fused: 4 nodes/wave, bf16 k/v gathers, GRU
__global__ __launch_bounds__(256) void fused_fast(
    const float* __restrict__ state, const float* __restrict__ inputs,
    const float* __restrict__ Wq, const float* __restrict__ bq,
    const float* __restrict__ Ws, const float* __restrict__ bs,
    const float* __restrict__ W1, const float* __restrict__ b1,
    const float* __restrict__ W2, const float* __restrict__ b2,
    const u16* __restrict__ kbuf, const u16* __restrict__ vbuf,
    const unsigned char* __restrict__ maskb,
    const int* __restrict__ off, const int* __restrict__ psrc,
    float* __restrict__ out) {
    int w = threadIdx.x >> 6, lane = threadIdx.x & 63;
    int gb = (blockIdx.x * 4 + w) * 4;        // 4 nodes per wave, same batch b
    int b = gb / NN;
    __shared__ float xs[4][4][66];            // x rows; later h2 rows
    __shared__ float qs[4][4][64];            // q rows; later reset*h2 rows

    float xin[4]; bool mg[4];
#pragma unroll
    for (int j = 0; j < 4; ++j) {
        int g = gb + j;
        xs[w][j][lane] = state[(size_t)g * UU + lane];
        if (lane == 0) xs[w][j][64] = inputs[g];
    }
    __syncthreads();                          // A (uniform)
#pragma unroll
    for (int j = 0; j < 4; ++j) { xin[j] = xs[w][j][64]; mg[j] = (xs[w][j][58] != 0.0f); }

    // q (pre-scaled) + sproj for 4 nodes; weight value loaded once
    float aq[4], as_[4];
#pragma unroll
    for (int j = 0; j < 4; ++j) { aq[j] = 0.f; as_[j] = 0.f; }
    for (int f = 0; f < FF; ++f) {
        float wq = Wq[f * UU + lane], ws = Ws[f * UU + lane];
#pragma unroll
        for (int j = 0; j < 4; ++j) {
            float xv = xs[w][j][f];
            aq[j] += xv * wq; as_[j] += xv * ws;
        }
    }
    float bql = bq[lane], bsl = bs[lane];
#pragma unroll
    for (int j = 0; j < 4; ++j) {
        aq[j] = (aq[j] + bql) * SCALE_F;
        as_[j] += bsl;
        qs[w][j][lane] = aq[j];
    }
    __syncthreads();                          // B (uniform)

    const unsigned char* mb = maskb + (size_t)b * NN;
    const u16* kb = kbuf + (size_t)b * NN * UU;
    const u16* vb = vbuf + (size_t)b * NN * UU;

#pragma unroll 1
    for (int j = 0; j < 4; ++j) {
        float h2;
        if (mg[j]) {
            int n = gb + j - b * NN;
            int i0 = off[n], i1 = off[n + 1];
            i0 = max(0, min(i0, EE)); i1 = max(i0, min(i1, EE));
            float m = NEG_F, l = 0.f;
            float ac0 = 0.f, ac1 = 0.f, ac2 = 0.f, ac3 = 0.f;
            for (int i = i0; i < i1; i += 64) {
                int tlen = min(64, i1 - i);
                // phase A: lane = edge; k row = 128 B (2 cache lines)
                float sc = NEG_F; bool act = false; int srow = 0;
                if (lane < tlen) {
                    int s = psrc[i + lane];
                    if ((unsigned)s < (unsigned)NN && mb[s]) {
                        srow = s; act = true;
                        const uint4* kp = (const uint4*)(kb + (size_t)s * UU);
                        float d0 = 0.f, d1 = 0.f, d2 = 0.f, d3 = 0.f;
#pragma unroll
                        for (int c = 0; c < 8; ++c) {
                            uint4 kk = kp[c];
                            const float4 qa = *(const float4*)&qs[w][j][c * 8];
                            const float4 qb = *(const float4*)&qs[w][j][c * 8 + 4];
                            d0 += u2f(kk.x << 16) * qa.x; d1 += u2f(kk.x & 0xFFFF0000u) * qa.y;
                            d2 += u2f(kk.y << 16) * qa.z; d3 += u2f(kk.y & 0xFFFF0000u) * qa.w;
                            d0 += u2f(kk.z << 16) * qb.x; d1 += u2f(kk.z & 0xFFFF0000u) * qb.y;
                            d2 += u2f(kk.w << 16) * qb.z; d3 += u2f(kk.w & 0xFFFF0000u) * qb.w;
                        }
                        sc = (d0 + d1) + (d2 + d3);
                    }
                }
                // tile softmax merge: 2 butterflies (max, sum)
                float mt = sc;
#pragma unroll
                for (int d = 1; d < 64; d <<= 1) mt = fmaxf(mt, __shfl_xor(mt, d, 64));
                float mnew = fmaxf(m, mt);
                float scale = __expf(m - mnew);   // m=NEG,mnew=NEG -> 1, l=0 ok
                float p = act ? __expf(sc - mnew) : 0.f;
                float ps = p;
#pragma unroll
                for (int d = 1; d < 64; d <<= 1) ps += __shfl_xor(ps, d, 64);
                l = l * scale + ps;
                m = mnew;
                // phase B: lane = channel; v rows coalesced 128 B
                ac0 *= scale; ac1 *= scale; ac2 *= scale; ac3 *= scale;
                for (int j0 = 0; j0 < 64; j0 += 8) {
                    if (j0 >= tlen) break;        // uniform
#pragma unroll
                    for (int jj = 0; jj < 8; ++jj) {
                        float pj = __shfl(p, j0 + jj, 64);
                        int   sj = __shfl(srow, j0 + jj, 64);
                        float vv = u2f((unsigned)vb[(size_t)sj * UU + lane] << 16);
                        if ((jj & 3) == 0) ac0 += pj * vv;
                        else if ((jj & 3) == 1) ac1 += pj * vv;
                        else if ((jj & 3) == 2) ac2 += pj * vv;
                        else ac3 += pj * vv;
                    }
                }
            }
            float acc = (ac0 + ac1) + (ac2 + ac3);
            float agg = (l > 0.f) ? acc / fmaxf(l, 1e-16f) : 0.f;
            h2 = agg + as_[j];
        } else {
            h2 = xs[w][j][lane];              // masked node: pass-through h
        }
        xs[w][j][lane] = h2;                  // own slot; [64]=xin preserved
    }
    __syncthreads();                          // C (uniform)

    // GRU: value = sigmoid([xin,h2]@W1+b1), c = tanh([xin,r*h2]@W2+b2)
    float a1[4], a2[4];
#pragma unroll
    for (int j = 0; j < 4; ++j) { a1[j] = xin[j] * W1[lane]; a2[j] = xin[j] * W1[UU + lane]; }
    for (int f = 0; f < UU; ++f) {
        float w1a = W1[(f + 1) * 128 + lane], w1b = W1[(f + 1) * 128 + UU + lane];
#pragma unroll
        for (int j = 0; j < 4; ++j) {
            float hv = xs[w][j][f];
            a1[j] += hv * w1a; a2[j] += hv * w1b;
        }
    }
    float b1a = b1[lane], b1b = b1[UU + lane];
    float rst[4], z[4];
#pragma unroll
    for (int j = 0; j < 4; ++j) {
        rst[j] = 1.f / (1.f + __expf(-(a1[j] + b1a)));
        z[j]   = 1.f / (1.f + __expf(-(a2[j] + b1b)));
        qs[w][j][lane] = rst[j] * xs[w][j][lane];   // reset*h2
    }
    __syncthreads();                          // D (uniform)

    float a3[4];
#pragma unroll
    for (int j = 0; j < 4; ++j) a3[j] = xin[j] * W2[lane];
    for (int f = 0; f < UU; ++f) {
        float w2v = W2[(f + 1) * UU + lane];
#pragma unroll
        for (int j = 0; j < 4; ++j) a3[j] += qs[w][j][f] * w2v;
    }
    float b2l = b2[lane];
#pragma unroll
    for (int j = 0; j < 4; ++j) {
        float a = a3[j] + b2l;
        float aa = fabsf(a), tt = __expf(-2.f * aa);
        float c = copysignf((1.f - tt) / (1.f + tt), a);
        float h2v = xs[w][j][lane];
        out[(size_t)(gb + j) * UU + lane] = (1.f - z[j]) * h2v + z[j] * c;
    }
}

// -------------------- fallback (r7-proven): 1 node/wave, kv-free folded
__global__ __launch_bounds__(256) void fused_kernel(
    const float* __restrict__ state, const float* __restrict__ inputs,
    const float* __restrict__ Wq, const float* __restrict__ bq,
    const float* __restrict__ Wk, const float* __restrict__ WkT,
    const float* __restrict__ bk,
    const float* __restrict__ Wv, const float* __restrict__ bv,
    const float* __restrict__ Ws, const float* __restrict__ bs,
    const float* __restrict__ W1, const float* __restrict__ b1,
    const float* __restrict__ W2, const float* __restrict__ b2,
    const int* __restrict__ off, const int* __restrict__ psrc,
    float* __restrict__ out) {
    int w = threadIdx.x >> 6, lane = threadIdx.x & 63;
    int g = blockIdx.x * 4 + w;
    int b = g / NN, n = g - b * NN;
    size_t o = (size_t)g * UU + lane;
    __shared__ float xsL[4][68];
    __shared__ float qsL[4][64];
    __shared__ float h2L[4][64];

    float hval = state[o];
    float xinv = inputs[g];
    xsL[w][lane] = hval;
    if (lane == 0) xsL[w][64] = xinv;
    __syncthreads();

    float aq = 0.f, as_ = 0.f;
    for (int f = 0; f < FF; ++f) {
        float xv = xsL[w][f];
        aq  += xv * Wq[f * UU + lane];
        as_ += xv * Ws[f * UU + lane];
    }
    aq = (aq + bq[lane]) * SCALE_F;
    as_ += bs[lane];
    qsL[w][lane] = aq;
    __syncthreads();

    float qk = 0.f;
    for (int u = 0; u < UU; ++u)
        qk += WkT[u * UU + lane] * qsL[w][u];
    float t64 = Wk[UU * UU + lane] * aq;
    float tbk = bk[lane] * aq;
#pragma unroll
    for (int d = 1; d < 64; d <<= 1) {
        t64 += __shfl_xor(t64, d, 64);
        tbk += __shfl_xor(tbk, d, 64);
    }
    float qbk = tbk;
    __syncthreads();
    xsL[w][lane] = qk;
    if (lane == 0) xsL[w][64] = t64;
    __syncthreads();

    bool mg = (__shfl(hval, 58, 64) != 0.0f);

    float m = NEG_F, l = 0.f, xax = 0.f;
    float acc0 = 0.f, acc1 = 0.f, acc2 = 0.f, acc3 = 0.f;
    if (mg) {
        int i0 = off[n], i1 = off[n + 1];
        i0 = max(0, min(i0, EE));
        i1 = max(i0, min(i1, EE));
        const float* stb = state  + (size_t)b * NN * UU;
        const float* inb = inputs + (size_t)b * NN;
        float qk64 = xsL[w][64];
        for (int i = i0; i < i1; i += 64) {
            int tlen = min(64, i1 - i);
            int  s_e  = (lane < tlen) ? psrc[i + lane] : -1;
            bool valid = ((unsigned)s_e < (unsigned)NN);
            int  srow = valid ? s_e : 0;
            float sc = NEG_F;
            float xins = 0.f;
            bool act = false;
            if (valid) {
                const float* rp = stb + (size_t)s_e * UU;
                float d0 = 0.f, d1 = 0.f, d2 = 0.f, d3 = 0.f, m58 = 0.f;
#pragma unroll
                for (int u4 = 0; u4 < 16; ++u4) {
                    float4 r  = *(const float4*)(rp + u4 * 4);
                    float4 qv = *(const float4*)&xsL[w][u4 * 4];
                    if (u4 == 14) m58 = r.z;
                    d0 += r.x * qv.x; d1 += r.y * qv.y;
                    d2 += r.z * qv.z; d3 += r.w * qv.w;
                }
                if (m58 != 0.f) {
                    act = true;
                    xins = inb[s_e];
                    sc = (d0 + d1) + (d2 + d3) + qk64 * xins + qbk;
                }
            }
            float mt = sc;
#pragma unroll
            for (int d = 1; d < 64; d <<= 1) mt = fmaxf(mt, __shfl_xor(mt, d, 64));
            float mnew = fmaxf(m, mt);
            float scale = __expf(m - mnew);
            float p = act ? __expf(sc - mnew) : 0.f;
            float ps = p, pxs = p * xins;
#pragma unroll
            for (int d = 1; d < 64; d <<= 1) {
                ps  += __shfl_xor(ps, d, 64);
                pxs += __shfl_xor(pxs, d, 64);
            }
            l   = l   * scale + ps;
            xax = xax * scale + pxs;
            m = mnew;
            acc0 *= scale; acc1 *= scale; acc2 *= scale; acc3 *= scale;
            for (int j0 = 0; j0 < 64; j0 += 8) {
                if (j0 >= tlen) break;
#pragma unroll
                for (int jj = 0; jj < 8; ++jj) {
                    int j = j0 + jj;
                    float pj = __shfl(p, j, 64);
                    int   sj = __shfl(srow, j, 64);
                    float hv = stb[(size_t)sj * UU + lane];
                    if ((jj & 3) == 0) acc0 += pj * hv;
                    else if ((jj & 3) == 1) acc1 += pj * hv;
                    else if ((jj & 3) == 2) acc2 += pj * hv;
                    else acc3 += pj * hv;
                }
            }
        }
    }
    qsL[w][lane] = (acc0 + acc1) + (acc2 + acc3);
    __syncthreads();

    float h2;
    if (mg) {
        float agg = 0.f;
        if (l > 0.f) {
            float num = 0.f;
            for (int f = 0; f < UU; ++f)
                num += Wv[f * UU + lane] * qsL[w][f];
            num += Wv[UU * UU + lane] * xax;
            agg = num / fmaxf(l, 1e-16f) + bv[lane];
        }
        h2 = agg + as_;
    } else {
        h2 = hval;
    }

    h2L[w][lane] = h2;
    __syncthreads();

    float a1 = xinv * W1[lane];
    float a2 = xinv * W1[UU + lane];
    for (int f = 0; f < UU; ++f) {
        float hv = h2L[w][f];
        a1 += hv * W1[(f + 1) * 128 + lane];
        a2 += hv * W1[(f + 1) * 128 + UU + lane];
    }
    a1 += b1[lane];
    a2 += b1[UU + lane];
    float reset = 1.f / (1.f + __expf(-a1));
    float z     = 1.f / (1.f + __expf(-a2));

    __syncthreads();
    h2L[w][lane] = reset * h2;
    __syncthreads();

    float a3 = xinv * W2[lane];
    for (int f = 0; f < UU; ++f)
        a3 += h2L[w][f] * W2[(f + 1) * UU + lane];
    a3 += b2[lane];
    float aa = fabsf(a3);
    float tt = __expf(-2.f * aa);
    float c  = copysignf((1.f - tt) / (1.f + tt), a3);

    out[o] = (1.f - z) * h2 + z * c;
}

// ------------------------------------------------------------------- launch
extern "C" void kernel_launch(void* const* d_in, const int* in_sizes, int n_in,
                              void* d_out, int out_size, void* d_ws, size_t ws_size,
                              hipStream_t stream) {
    const float* inputs = (const float*)d_in[0];
    const float* state  = (const float*)d_in[1];
    if (in_sizes[0] != BB * NN) { inputs = (const float*)d_in[1]; state = (const float*)d_in[0]; }
    const int*   esrc   = (const int*)d_in[2];
    const int*   edst   = (const int*)d_in[3];
    const float* Wq = (const float*)d_in[4];
    const float* bq = (const float*)d_in[5];
    const float* Wk = (const float*)d_in[6];
    const float* bk = (const float*)d_in[7];
    const float* Wv = (const float*)d_in[8];
    const float* bv = (const float*)d_in[9];
    const float* Ws = (const float*)d_in[10];
    const float* bs = (const float*)d_in[11];
    const float* W1 = (const float*)d_in[12];
    const float* b1 = (const float*)d_in[13];
    const float* W2 = (const float*)d_in[14];
    const float* b2 = (const float*)d_in[15];
    float* out = (float*)d_out;

    // workspace carve: CSR (proven) + WkT + mask + bf16 k/v (fast path)
    char* base = (char*)d_ws;
    size_t ofs = 0;
    int* counts = (int*)(base + ofs); ofs = align_up(ofs + (size_t)NN * 4);
    int* offp   = (int*)(base + ofs); ofs = align_up(ofs + (size_t)(NN + 1) * 4);
    int* cursor = (int*)(base + ofs); ofs = align_up(ofs + (size_t)NN * 4);
    int* psrc   = (int*)(base + ofs); ofs = align_up(ofs + (size_t)EE * 4);
    float* WkT  = (float*)(base + ofs); ofs = align_up(ofs + (size_t)UU * UU * 4);
    size_t ofs_small = ofs;
    unsigned char* maskb = (unsigned char*)(base + ofs); ofs = align_up(ofs + (size_t)BB * NN);
    u16* kbuf = (u16*)(base + ofs); ofs = align_up(ofs + (size_t)BB * NN * UU * 2);
    u16* vbuf = (u16*)(base + ofs); ofs = align_up(ofs + (size_t)BB * NN * UU * 2);
    size_t ofs_fast = ofs;
    (void)n_in; (void)out_size;

    bool fast = (ws_size >= ofs_fast) && (ws_size >= ofs_small);

    hipMemsetAsync(counts, 0, (size_t)NN * 4, stream);
    hist_kernel<<<(EE + 255) / 256, 256, 0, stream>>>(edst, counts);
    scan_kernel<<<1, 1024, 0, stream>>>(counts, offp, cursor);
    scatter_kernel<<<(EE + 255) / 256, 256, 0, stream>>>(edst, esrc, cursor, psrc);

    if (fast) {
        prep_kernel<<<(BB * NN) / 32, 256, 0, stream>>>(state, inputs, Wk, bk,
                                                        Wv, bv, kbuf, vbuf, maskb);
        fused_fast<<<(BB * NN) / 16, 256, 0, stream>>>(state, inputs, Wq, bq,
                                                       Ws, bs, W1, b1, W2, b2,
                                                       kbuf, vbuf, maskb,
                                                       offp, psrc, out);
    } else {
        wkt_kernel<<<(UU * UU + 255) / 256, 256, 0, stream>>>(Wk, WkT);
        fused_kernel<<<(BB * NN) / 4, 256, 0, stream>>>(state, inputs, Wq, bq,
                                                        Wk, WkT, bk, Wv, bv,
                                                        Ws, bs, W1, b1, W2, b2,
                                                        offp, psrc, out);
    }
}